// Round 1
// baseline (137.340 us; speedup 1.0000x reference)
//
#include <hip/hip_runtime.h>

// Problem constants (from reference)
#define BATCH 16
#define CIN   64
#define H     64
#define W     64
#define OCH   128
#define NLEAF 16      // 2^TREE_DEPTH
#define NGATE 15      // N-1
#define OH    64
#define OW    64
#define PH    32
#define PW    32

__device__ __constant__ float OP2POLY[16][4] = {
    {0, 0, 0, 0}, {0, 0, 0, 1}, {0, 1, 0, -1}, {0, 1, 0, 0},
    {0, 0, 1, -1}, {0, 0, 1, 0}, {0, 1, 1, -2}, {0, 1, 1, -1},
    {1, -1, -1, 1}, {1, -1, -1, 2}, {1, 0, -1, 0}, {1, 0, -1, 1},
    {1, -1, 0, 0}, {1, -1, 0, 1}, {1, 0, 0, -1}, {1, 0, 0, 0}};

// Forward value of w is exactly w_hard (one-hot of argmax), so
// coeffs[o][g][:] = OP2POLY[argmax(weights[o][g][:])].
__global__ __launch_bounds__(256) void prep_coeffs(
    const float* __restrict__ weights,  // (OC, 15, 16)
    float* __restrict__ coeffs)         // (OC, 15, 4)
{
    int g = blockIdx.x * 256 + threadIdx.x;
    if (g >= OCH * NGATE) return;
    const float* wp = weights + g * 16;
    int best = 0;
    float bv = wp[0];
#pragma unroll
    for (int k = 1; k < 16; ++k) {
        float v = wp[k];
        if (v > bv) { bv = v; best = k; }   // strict > keeps first max (jnp.argmax)
    }
    float4 r = make_float4(OP2POLY[best][0], OP2POLY[best][1],
                           OP2POLY[best][2], OP2POLY[best][3]);
    reinterpret_cast<float4*>(coeffs)[g] = r;
}

// One wave (64 lanes) handles one (b, oc, row-pair io): lane = column j.
// Each lane computes pre-pool pixels y[2*io][j], y[2*io+1][j], pools rows
// in-register, then pools column pairs via shfl_xor(1).
__global__ __launch_bounds__(256) void logic_tree_main(
    const float* __restrict__ x,        // (B, Cin, H, W)
    const float* __restrict__ coeffs,   // (OC, 15, 4)
    const int* __restrict__ ci,         // (OC, 16)
    const int* __restrict__ px,         // (OC, 16)
    const int* __restrict__ py,         // (OC, 16)
    float* __restrict__ out)            // (B, OC, 32, 32)
{
    // block -> 4 waves; all 4 waves share (b, oc), io = (blk%8)*4 + wave
    int blk = blockIdx.x;
    int oc = (blk >> 3) & (OCH - 1);
    int b  = blk >> 10;                   // blk / (8*128)
    int iobase = (blk & 7) << 2;

    __shared__ float sc[NGATE][4];
    __shared__ int sch[NLEAF];
    __shared__ int sdy[NLEAF];
    __shared__ int sdx[NLEAF];

    int tid = threadIdx.x;
    if (tid < NGATE * 4) (&sc[0][0])[tid] = coeffs[oc * (NGATE * 4) + tid];
    if (tid >= 64 && tid < 64 + NLEAF)  sch[tid - 64]  = ci[oc * NLEAF + (tid - 64)];
    if (tid >= 96 && tid < 96 + NLEAF)  sdy[tid - 96]  = py[oc * NLEAF + (tid - 96)] - 1;
    if (tid >= 128 && tid < 128 + NLEAF) sdx[tid - 128] = px[oc * NLEAF + (tid - 128)] - 1;
    __syncthreads();

    int wave = tid >> 6;
    int lane = tid & 63;
    int io = iobase + wave;               // output row in [0,32)
    const float* xb = x + (size_t)b * CIN * H * W;

    float pr = 1.0f;                      // prod over the two rows of (1 - y)
#pragma unroll
    for (int half = 0; half < 2; ++half) {
        int i = io * 2 + half;            // pre-pool row
        float v[NLEAF];
#pragma unroll
        for (int n = 0; n < NLEAF; ++n) {
            int r = i + sdy[n];
            int c = lane + sdx[n];
            float val = 0.0f;
            if ((unsigned)r < (unsigned)H && (unsigned)c < (unsigned)W)
                val = xb[(sch[n] * H + r) * W + c];
            v[n] = val;
        }
        int goff = 0;
#pragma unroll
        for (int nlev = 8; nlev >= 1; nlev >>= 1) {
#pragma unroll
            for (int g = 0; g < 8; ++g) {
                if (g < nlev) {
                    float a = v[2 * g], bb = v[2 * g + 1];
                    v[g] = sc[goff + g][0] + sc[goff + g][1] * a +
                           sc[goff + g][2] * bb + sc[goff + g][3] * (a * bb);
                }
            }
            goff += nlev;
        }
        pr *= (1.0f - v[0]);
    }
    // pool column pairs: lanes (2j, 2j+1)
    float pother = __shfl_xor(pr, 1, 64);
    float p = pr * pother;
    if ((lane & 1) == 0) {
        int jo = lane >> 1;
        out[(((size_t)b * OCH + oc) * PH + io) * PW + jo] = 1.0f - p;
    }
}

extern "C" void kernel_launch(void* const* d_in, const int* in_sizes, int n_in,
                              void* d_out, int out_size, void* d_ws, size_t ws_size,
                              hipStream_t stream) {
    const float* x       = (const float*)d_in[0];
    const float* weights = (const float*)d_in[1];
    const int*   ci      = (const int*)d_in[2];
    const int*   px      = (const int*)d_in[3];
    const int*   py      = (const int*)d_in[4];
    float* out = (float*)d_out;
    float* coeffs = (float*)d_ws;    // OC*15*4 floats = 30720 B

    prep_coeffs<<<(OCH * NGATE + 255) / 256, 256, 0, stream>>>(weights, coeffs);

    int nblocks = BATCH * OCH * 8;   // 4 row-pair waves per block, 32 row-pairs per (b,oc)
    logic_tree_main<<<nblocks, 256, 0, stream>>>(x, coeffs, ci, px, py, out);
}

// Round 2
// 113.380 us; speedup vs baseline: 1.2113x; 1.2113x over previous
//
#include <hip/hip_runtime.h>

// Problem constants
#define BATCH 16
#define CIN   64
#define H     64
#define W     64
#define OCH   128
#define NLEAF 16
#define NGATE 15
#define PH    32
#define PW    32
// padded input: (B, Cin, 66, 66), halo of 1 on each side (zeros)
#define XPH   66
#define XPW   66
#define XPIMG (XPH * XPW)                       // 4356
#define XP_ELEMS (BATCH * CIN * XPIMG)          // 4,460,544 floats
#define COEFF_OFF XP_ELEMS                      // float offset in ws
#define COEFF_ELEMS (OCH * NGATE * 4)           // 7680
#define LEAF_OFF (COEFF_OFF + COEFF_ELEMS)      // int offset in ws (aliased)
#define LEAF_ELEMS (OCH * NLEAF)                // 2048
#define WS_NEED_BYTES ((size_t)(XP_ELEMS + COEFF_ELEMS + LEAF_ELEMS) * 4)

__device__ __constant__ float OP2POLY[16][4] = {
    {0, 0, 0, 0}, {0, 0, 0, 1}, {0, 1, 0, -1}, {0, 1, 0, 0},
    {0, 0, 1, -1}, {0, 0, 1, 0}, {0, 1, 1, -2}, {0, 1, 1, -1},
    {1, -1, -1, 1}, {1, -1, -1, 2}, {1, 0, -1, 0}, {1, 0, -1, 1},
    {1, -1, 0, 0}, {1, -1, 0, 1}, {1, 0, 0, -1}, {1, 0, 0, 0}};

// ---------------------------------------------------------------------------
// Kernel 1: build padded x in ws (zeros in the halo) + per-oc prep
// (coeffs = OP2POLY[argmax(weights)] and leaf element offsets) done by the
// first OCH blocks.
// ---------------------------------------------------------------------------
__global__ __launch_bounds__(256) void pad_prep(
    const float* __restrict__ x,        // (B, Cin, 64, 64)
    const float* __restrict__ weights,  // (OC, 15, 16)
    const int* __restrict__ ci,         // (OC, 16)
    const int* __restrict__ px,         // (OC, 16)
    const int* __restrict__ py,         // (OC, 16)
    float* __restrict__ ws)
{
    int blk = blockIdx.x, tid = threadIdx.x;
    int idx = blk * 256 + tid;
    if (idx < XP_ELEMS) {
        int c   = idx % XPW;
        int t   = idx / XPW;
        int r   = t % XPH;
        int img = t / XPH;               // b*CIN + ch
        float v = 0.0f;
        if ((unsigned)(r - 1) < (unsigned)H && (unsigned)(c - 1) < (unsigned)W)
            v = x[(size_t)img * (H * W) + (r - 1) * W + (c - 1)];
        ws[idx] = v;
    }
    if (blk < OCH) {
        int oc = blk;
        if (tid < NGATE) {
            const float* wp = weights + (oc * NGATE + tid) * 16;
            int best = 0;
            float bv = wp[0];
#pragma unroll
            for (int k = 1; k < 16; ++k) {
                float v = wp[k];
                if (v > bv) { bv = v; best = k; }  // first-max, like jnp.argmax
            }
            float* cdst = ws + COEFF_OFF + (oc * NGATE + tid) * 4;
            cdst[0] = OP2POLY[best][0];
            cdst[1] = OP2POLY[best][1];
            cdst[2] = OP2POLY[best][2];
            cdst[3] = OP2POLY[best][3];
        } else if (tid >= 64 && tid < 64 + NLEAF) {
            int n = tid - 64;
            int lb = (ci[oc * NLEAF + n] * XPH + py[oc * NLEAF + n]) * XPW +
                     px[oc * NLEAF + n];
            ((int*)ws)[LEAF_OFF + oc * NLEAF + n] = lb;
        }
    }
}

// ---------------------------------------------------------------------------
// Kernel 2: main. Block = (b, oc); wave w handles pre-pool rows [16w,16w+16),
// lane = column. Coeffs + leaf offsets forced into SGPRs (wave-uniform);
// leaf loads use one VGPR offset per leaf + 13-bit immediate row offsets.
// No bounds checks (halo-padded input).
// ---------------------------------------------------------------------------
__global__ __launch_bounds__(256) void logic_tree_pad(
    const float* __restrict__ ws,
    float* __restrict__ out)            // (B, OC, 32, 32)
{
    int blk = blockIdx.x;
    int oc = blk & (OCH - 1);
    int b  = blk >> 7;

    const float* cw = ws + COEFF_OFF + oc * (NGATE * 4);
    const int*   lbp = ((const int*)ws) + LEAF_OFF + oc * NLEAF;
    const float* xb = ws + (size_t)b * (CIN * XPIMG);

    int tid  = threadIdx.x;
    int wave = tid >> 6;
    int lane = tid & 63;
    int row0 = wave << 4;

    // force wave-uniform values into SGPRs
    float C[NGATE * 4];
#pragma unroll
    for (int i = 0; i < NGATE * 4; ++i) {
        int u = __builtin_amdgcn_readfirstlane(__builtin_bit_cast(int, cw[i]));
        C[i] = __builtin_bit_cast(float, u);
    }
    int LB[NLEAF];
#pragma unroll
    for (int n = 0; n < NLEAF; ++n)
        LB[n] = __builtin_amdgcn_readfirstlane(lbp[n]);

    // per-leaf vector offsets (row0, lane folded in once)
    const float* P[NLEAF];
#pragma unroll
    for (int n = 0; n < NLEAF; ++n)
        P[n] = xb + (LB[n] + row0 * XPW + lane);

    size_t obase = (((size_t)b * OCH + oc) * PH + (row0 >> 1)) * PW + (lane >> 1);

    float pprev = 0.0f;
#pragma unroll
    for (int k = 0; k < 16; ++k) {
        float v[NLEAF];
#pragma unroll
        for (int n = 0; n < NLEAF; ++n)
            v[n] = P[n][k * XPW];       // immediate offset k*264 bytes
        int go = 0;
#pragma unroll
        for (int lev = 8; lev >= 1; lev >>= 1) {
#pragma unroll
            for (int g = 0; g < 8; ++g) {
                if (g < lev) {
                    float a = v[2 * g], bb = v[2 * g + 1];
                    v[g] = C[(go + g) * 4] + C[(go + g) * 4 + 1] * a +
                           C[(go + g) * 4 + 2] * bb + C[(go + g) * 4 + 3] * (a * bb);
                }
            }
            go += lev;
        }
        float q = 1.0f - v[0];
        if (k & 1) {
            float p = pprev * q;                  // row-pair product of (1-y)
            float pp = p * __shfl_xor(p, 1, 64);  // column-pair product
            if (!(lane & 1))
                out[obase + (size_t)(k >> 1) * PW] = 1.0f - pp;
        } else {
            pprev = q;
        }
    }
}

// ---------------------------------------------------------------------------
// Fallback (round-1 kernels) in case ws is too small for the padded copy.
// ---------------------------------------------------------------------------
__global__ __launch_bounds__(256) void prep_coeffs_fb(
    const float* __restrict__ weights, float* __restrict__ coeffs)
{
    int g = blockIdx.x * 256 + threadIdx.x;
    if (g >= OCH * NGATE) return;
    const float* wp = weights + g * 16;
    int best = 0; float bv = wp[0];
#pragma unroll
    for (int k = 1; k < 16; ++k) { float v = wp[k]; if (v > bv) { bv = v; best = k; } }
    float4 r = make_float4(OP2POLY[best][0], OP2POLY[best][1],
                           OP2POLY[best][2], OP2POLY[best][3]);
    reinterpret_cast<float4*>(coeffs)[g] = r;
}

__global__ __launch_bounds__(256) void logic_tree_fb(
    const float* __restrict__ x, const float* __restrict__ coeffs,
    const int* __restrict__ ci, const int* __restrict__ px,
    const int* __restrict__ py, float* __restrict__ out)
{
    int blk = blockIdx.x;
    int oc = (blk >> 3) & (OCH - 1);
    int b  = blk >> 10;
    int iobase = (blk & 7) << 2;
    __shared__ float sc[NGATE][4];
    __shared__ int sch[NLEAF], sdy[NLEAF], sdx[NLEAF];
    int tid = threadIdx.x;
    if (tid < NGATE * 4) (&sc[0][0])[tid] = coeffs[oc * (NGATE * 4) + tid];
    if (tid >= 64 && tid < 64 + NLEAF)  sch[tid - 64]  = ci[oc * NLEAF + (tid - 64)];
    if (tid >= 96 && tid < 96 + NLEAF)  sdy[tid - 96]  = py[oc * NLEAF + (tid - 96)] - 1;
    if (tid >= 128 && tid < 128 + NLEAF) sdx[tid - 128] = px[oc * NLEAF + (tid - 128)] - 1;
    __syncthreads();
    int wave = tid >> 6, lane = tid & 63;
    int io = iobase + wave;
    const float* xbp = x + (size_t)b * CIN * H * W;
    float pr = 1.0f;
#pragma unroll
    for (int half = 0; half < 2; ++half) {
        int i = io * 2 + half;
        float v[NLEAF];
#pragma unroll
        for (int n = 0; n < NLEAF; ++n) {
            int r = i + sdy[n], c = lane + sdx[n];
            float val = 0.0f;
            if ((unsigned)r < (unsigned)H && (unsigned)c < (unsigned)W)
                val = xbp[(sch[n] * H + r) * W + c];
            v[n] = val;
        }
        int goff = 0;
#pragma unroll
        for (int nlev = 8; nlev >= 1; nlev >>= 1) {
#pragma unroll
            for (int g = 0; g < 8; ++g) {
                if (g < nlev) {
                    float a = v[2 * g], bb = v[2 * g + 1];
                    v[g] = sc[goff + g][0] + sc[goff + g][1] * a +
                           sc[goff + g][2] * bb + sc[goff + g][3] * (a * bb);
                }
            }
            goff += nlev;
        }
        pr *= (1.0f - v[0]);
    }
    float pother = __shfl_xor(pr, 1, 64);
    float p = pr * pother;
    if ((lane & 1) == 0)
        out[(((size_t)b * OCH + oc) * PH + io) * PW + (lane >> 1)] = 1.0f - p;
}

extern "C" void kernel_launch(void* const* d_in, const int* in_sizes, int n_in,
                              void* d_out, int out_size, void* d_ws, size_t ws_size,
                              hipStream_t stream) {
    const float* x       = (const float*)d_in[0];
    const float* weights = (const float*)d_in[1];
    const int*   ci      = (const int*)d_in[2];
    const int*   px      = (const int*)d_in[3];
    const int*   py      = (const int*)d_in[4];
    float* out = (float*)d_out;

    if (ws_size >= WS_NEED_BYTES) {
        float* ws = (float*)d_ws;
        int pad_blocks = (XP_ELEMS + 255) / 256;   // 17424 (>= OCH, covers prep)
        pad_prep<<<pad_blocks, 256, 0, stream>>>(x, weights, ci, px, py, ws);
        logic_tree_pad<<<BATCH * OCH, 256, 0, stream>>>(ws, out);
    } else {
        float* coeffs = (float*)d_ws;              // 30 KB
        prep_coeffs_fb<<<(OCH * NGATE + 255) / 256, 256, 0, stream>>>(weights, coeffs);
        logic_tree_fb<<<BATCH * OCH * 8, 256, 0, stream>>>(x, coeffs, ci, px, py, out);
    }
}

// Round 3
// 107.931 us; speedup vs baseline: 1.2725x; 1.0505x over previous
//
#include <hip/hip_runtime.h>

// Problem constants
#define BATCH 16
#define CIN   64
#define H     64
#define W     64
#define OCH   128
#define NLEAF 16
#define NGATE 15
#define PH    32
#define PW    32
// padded input: (B, Cin, 66, 66), halo of 1 on each side (zeros)
#define XPH   66
#define XPW   66
#define XPIMG (XPH * XPW)                       // 4356
#define XP_ELEMS (BATCH * CIN * XPIMG)          // 4,460,544 floats
#define COEFF_OFF XP_ELEMS                      // float offset in ws
#define COEFF_ELEMS (OCH * NGATE * 4)           // 7680
#define LEAF_OFF (COEFF_OFF + COEFF_ELEMS)      // int offset in ws (aliased)
#define LEAF_ELEMS (OCH * NLEAF)                // 2048
#define WS_NEED_BYTES ((size_t)(XP_ELEMS + COEFF_ELEMS + LEAF_ELEMS) * 4)

__device__ __constant__ float OP2POLY[16][4] = {
    {0, 0, 0, 0}, {0, 0, 0, 1}, {0, 1, 0, -1}, {0, 1, 0, 0},
    {0, 0, 1, -1}, {0, 0, 1, 0}, {0, 1, 1, -2}, {0, 1, 1, -1},
    {1, -1, -1, 1}, {1, -1, -1, 2}, {1, 0, -1, 0}, {1, 0, -1, 1},
    {1, -1, 0, 0}, {1, -1, 0, 1}, {1, 0, 0, -1}, {1, 0, 0, 0}};

// ---------------------------------------------------------------------------
// Kernel 1: build padded x in ws (zeros in the halo) + per-oc prep
// (coeffs = OP2POLY[argmax(weights)] and leaf element offsets).
// ---------------------------------------------------------------------------
__global__ __launch_bounds__(256) void pad_prep(
    const float* __restrict__ x,        // (B, Cin, 64, 64)
    const float* __restrict__ weights,  // (OC, 15, 16)
    const int* __restrict__ ci,         // (OC, 16)
    const int* __restrict__ px,         // (OC, 16)
    const int* __restrict__ py,         // (OC, 16)
    float* __restrict__ ws)
{
    int blk = blockIdx.x, tid = threadIdx.x;
    int idx = blk * 256 + tid;
    if (idx < XP_ELEMS) {
        int c   = idx % XPW;
        int t   = idx / XPW;
        int r   = t % XPH;
        int img = t / XPH;               // b*CIN + ch
        float v = 0.0f;
        if ((unsigned)(r - 1) < (unsigned)H && (unsigned)(c - 1) < (unsigned)W)
            v = x[(size_t)img * (H * W) + (r - 1) * W + (c - 1)];
        ws[idx] = v;
    }
    if (blk < OCH) {
        int oc = blk;
        if (tid < NGATE) {
            const float* wp = weights + (oc * NGATE + tid) * 16;
            int best = 0;
            float bv = wp[0];
#pragma unroll
            for (int k = 1; k < 16; ++k) {
                float v = wp[k];
                if (v > bv) { bv = v; best = k; }  // first-max, like jnp.argmax
            }
            float* cdst = ws + COEFF_OFF + (oc * NGATE + tid) * 4;
            cdst[0] = OP2POLY[best][0];
            cdst[1] = OP2POLY[best][1];
            cdst[2] = OP2POLY[best][2];
            cdst[3] = OP2POLY[best][3];
        } else if (tid >= 64 && tid < 64 + NLEAF) {
            int n = tid - 64;
            int lb = (ci[oc * NLEAF + n] * XPH + py[oc * NLEAF + n]) * XPW +
                     px[oc * NLEAF + n];
            ((int*)ws)[LEAF_OFF + oc * NLEAF + n] = lb;
        }
    }
}

// ---------------------------------------------------------------------------
// Kernel 2: main. XCD-aware swizzle: XCD x (= blk%8) handles batches 2x,2x+1,
// iterating all 128 oc of b=2x first, then b=2x+1 -> per-XCD L2 working set
// is one padded image (1.1 MB) at a time; the 537 MB gather stream hits L2.
// Block = (b, oc); wave w handles pre-pool rows [16w,16w+16), lane = column.
// ---------------------------------------------------------------------------
__global__ __launch_bounds__(256) void logic_tree_pad(
    const float* __restrict__ ws,
    float* __restrict__ out)            // (B, OC, 32, 32)
{
    int blk = blockIdx.x;
    int xcd = blk & 7;
    int j   = blk >> 3;                 // 0..255 within this XCD's sequence
    int b   = (xcd << 1) | (j >> 7);
    int oc  = j & 127;

    const float* cw = ws + COEFF_OFF + oc * (NGATE * 4);
    const int*   lbp = ((const int*)ws) + LEAF_OFF + oc * NLEAF;
    const float* xb = ws + (size_t)b * (CIN * XPIMG);

    int tid  = threadIdx.x;
    int wave = tid >> 6;
    int lane = tid & 63;
    int row0 = wave << 4;

    // force wave-uniform values into SGPRs
    float C[NGATE * 4];
#pragma unroll
    for (int i = 0; i < NGATE * 4; ++i) {
        int u = __builtin_amdgcn_readfirstlane(__builtin_bit_cast(int, cw[i]));
        C[i] = __builtin_bit_cast(float, u);
    }
    int LB[NLEAF];
#pragma unroll
    for (int n = 0; n < NLEAF; ++n)
        LB[n] = __builtin_amdgcn_readfirstlane(lbp[n]);

    // per-leaf vector base pointers (row0, lane folded in once)
    const float* P[NLEAF];
#pragma unroll
    for (int n = 0; n < NLEAF; ++n)
        P[n] = xb + (LB[n] + row0 * XPW + lane);

    size_t obase = (((size_t)b * OCH + oc) * PH + (row0 >> 1)) * PW + (lane >> 1);

    float pprev = 0.0f;
#pragma unroll
    for (int k = 0; k < 16; ++k) {
        float v[NLEAF];
#pragma unroll
        for (int n = 0; n < NLEAF; ++n)
            v[n] = P[n][k * XPW];       // immediate offset k*264 bytes
        int go = 0;
#pragma unroll
        for (int lev = 8; lev >= 1; lev >>= 1) {
#pragma unroll
            for (int g = 0; g < 8; ++g) {
                if (g < lev) {
                    float a = v[2 * g], bb = v[2 * g + 1];
                    v[g] = C[(go + g) * 4] + C[(go + g) * 4 + 1] * a +
                           C[(go + g) * 4 + 2] * bb + C[(go + g) * 4 + 3] * (a * bb);
                }
            }
            go += lev;
        }
        float q = 1.0f - v[0];
        if (k & 1) {
            float p = pprev * q;                  // row-pair product of (1-y)
            float pp = p * __shfl_xor(p, 1, 64);  // column-pair product
            if (!(lane & 1))
                out[obase + (size_t)(k >> 1) * PW] = 1.0f - pp;
        } else {
            pprev = q;
        }
    }
}

// ---------------------------------------------------------------------------
// Fallback (round-1 kernels) in case ws is too small for the padded copy.
// ---------------------------------------------------------------------------
__global__ __launch_bounds__(256) void prep_coeffs_fb(
    const float* __restrict__ weights, float* __restrict__ coeffs)
{
    int g = blockIdx.x * 256 + threadIdx.x;
    if (g >= OCH * NGATE) return;
    const float* wp = weights + g * 16;
    int best = 0; float bv = wp[0];
#pragma unroll
    for (int k = 1; k < 16; ++k) { float v = wp[k]; if (v > bv) { bv = v; best = k; } }
    float4 r = make_float4(OP2POLY[best][0], OP2POLY[best][1],
                           OP2POLY[best][2], OP2POLY[best][3]);
    reinterpret_cast<float4*>(coeffs)[g] = r;
}

__global__ __launch_bounds__(256) void logic_tree_fb(
    const float* __restrict__ x, const float* __restrict__ coeffs,
    const int* __restrict__ ci, const int* __restrict__ px,
    const int* __restrict__ py, float* __restrict__ out)
{
    int blk = blockIdx.x;
    int oc = (blk >> 3) & (OCH - 1);
    int b  = blk >> 10;
    int iobase = (blk & 7) << 2;
    __shared__ float sc[NGATE][4];
    __shared__ int sch[NLEAF], sdy[NLEAF], sdx[NLEAF];
    int tid = threadIdx.x;
    if (tid < NGATE * 4) (&sc[0][0])[tid] = coeffs[oc * (NGATE * 4) + tid];
    if (tid >= 64 && tid < 64 + NLEAF)  sch[tid - 64]  = ci[oc * NLEAF + (tid - 64)];
    if (tid >= 96 && tid < 96 + NLEAF)  sdy[tid - 96]  = py[oc * NLEAF + (tid - 96)] - 1;
    if (tid >= 128 && tid < 128 + NLEAF) sdx[tid - 128] = px[oc * NLEAF + (tid - 128)] - 1;
    __syncthreads();
    int wave = tid >> 6, lane = tid & 63;
    int io = iobase + wave;
    const float* xbp = x + (size_t)b * CIN * H * W;
    float pr = 1.0f;
#pragma unroll
    for (int half = 0; half < 2; ++half) {
        int i = io * 2 + half;
        float v[NLEAF];
#pragma unroll
        for (int n = 0; n < NLEAF; ++n) {
            int r = i + sdy[n], c = lane + sdx[n];
            float val = 0.0f;
            if ((unsigned)r < (unsigned)H && (unsigned)c < (unsigned)W)
                val = xbp[(sch[n] * H + r) * W + c];
            v[n] = val;
        }
        int goff = 0;
#pragma unroll
        for (int nlev = 8; nlev >= 1; nlev >>= 1) {
#pragma unroll
            for (int g = 0; g < 8; ++g) {
                if (g < nlev) {
                    float a = v[2 * g], bb = v[2 * g + 1];
                    v[g] = sc[goff + g][0] + sc[goff + g][1] * a +
                           sc[goff + g][2] * bb + sc[goff + g][3] * (a * bb);
                }
            }
            goff += nlev;
        }
        pr *= (1.0f - v[0]);
    }
    float pother = __shfl_xor(pr, 1, 64);
    float p = pr * pother;
    if ((lane & 1) == 0)
        out[(((size_t)b * OCH + oc) * PH + io) * PW + (lane >> 1)] = 1.0f - p;
}

extern "C" void kernel_launch(void* const* d_in, const int* in_sizes, int n_in,
                              void* d_out, int out_size, void* d_ws, size_t ws_size,
                              hipStream_t stream) {
    const float* x       = (const float*)d_in[0];
    const float* weights = (const float*)d_in[1];
    const int*   ci      = (const int*)d_in[2];
    const int*   px      = (const int*)d_in[3];
    const int*   py      = (const int*)d_in[4];
    float* out = (float*)d_out;

    if (ws_size >= WS_NEED_BYTES) {
        float* ws = (float*)d_ws;
        int pad_blocks = (XP_ELEMS + 255) / 256;   // 17424 (>= OCH, covers prep)
        pad_prep<<<pad_blocks, 256, 0, stream>>>(x, weights, ci, px, py, ws);
        logic_tree_pad<<<BATCH * OCH, 256, 0, stream>>>(ws, out);
    } else {
        float* coeffs = (float*)d_ws;              // 30 KB
        prep_coeffs_fb<<<(OCH * NGATE + 255) / 256, 256, 0, stream>>>(weights, coeffs);
        logic_tree_fb<<<BATCH * OCH * 8, 256, 0, stream>>>(x, coeffs, ci, px, py, out);
    }
}

// Round 4
// 98.600 us; speedup vs baseline: 1.3929x; 1.0946x over previous
//
#include <hip/hip_runtime.h>

// Problem constants
#define BATCH 16
#define CIN   64
#define H_    64
#define W_    64
#define IMG   (H_ * W_)      // 4096
#define OCH   128
#define NLEAF 16
#define NGATE 15
#define PH    32
#define PW    32

__device__ __constant__ float OP2POLY[16][4] = {
    {0, 0, 0, 0}, {0, 0, 0, 1}, {0, 1, 0, -1}, {0, 1, 0, 0},
    {0, 0, 1, -1}, {0, 0, 1, 0}, {0, 1, 1, -2}, {0, 1, 1, -1},
    {1, -1, -1, 1}, {1, -1, -1, 2}, {1, 0, -1, 0}, {1, 0, -1, 1},
    {1, -1, 0, 0}, {1, -1, 0, 1}, {1, 0, 0, -1}, {1, 0, 0, 0}};

static __device__ __forceinline__ float readlane_f(float v, int l) {
    return __builtin_bit_cast(float,
        __builtin_amdgcn_readlane(__builtin_bit_cast(int, v), l));
}

// Single fused kernel. Block = (b, oc) with XCD swizzle (blk%8 = XCD; each
// XCD walks all 128 oc of b=2x then b=2x+1 -> per-XCD L2 working set = one
// 1 MB x-image). Wave w = pre-pool rows [16w,16w+16), lane = column.
// Setup per block: lane g<15 argmaxes weights[oc][g][:]; v_readlane
// broadcasts the 60 OP2POLY coeffs into SGPRs. Leaf descriptors via scalar
// loads. Halo: clamped-col gather + 0/1 float masks; row OOB only at the
// peeled k=0 (wave 0, dy=-1) / k=15 (wave 3, dy=+1) iterations.
// k-loop software-pipelined: row k+1's 16 loads issue before row k's gates.
__global__ __launch_bounds__(256, 4) void logic_tree_fused(
    const float* __restrict__ x,        // (B, Cin, 64, 64)
    const float* __restrict__ weights,  // (OC, 15, 16)
    const int* __restrict__ ci,         // (OC, 16)
    const int* __restrict__ px,         // (OC, 16)
    const int* __restrict__ py,         // (OC, 16)
    float* __restrict__ out)            // (B, OC, 32, 32)
{
    const int blk = blockIdx.x;
    const int xcd = blk & 7;
    const int jj  = blk >> 3;
    const int b   = (xcd << 1) | (jj >> 7);
    const int oc  = jj & 127;

    const int tid  = threadIdx.x;
    const int wave = tid >> 6;
    const int lane = tid & 63;
    const int row0 = wave << 4;

    // ---- gate coefficients: lane g (<15) argmaxes weights[oc][g][0..15] ----
    const int g = (lane < NGATE) ? lane : 0;
    const float* wp = weights + (oc * NGATE + g) * 16;
    const float4 w0 = reinterpret_cast<const float4*>(wp)[0];
    const float4 w1 = reinterpret_cast<const float4*>(wp)[1];
    const float4 w2 = reinterpret_cast<const float4*>(wp)[2];
    const float4 w3 = reinterpret_cast<const float4*>(wp)[3];
    const float wv[16] = {w0.x, w0.y, w0.z, w0.w, w1.x, w1.y, w1.z, w1.w,
                          w2.x, w2.y, w2.z, w2.w, w3.x, w3.y, w3.z, w3.w};
    int best = 0;
    float bv = wv[0];
#pragma unroll
    for (int k = 1; k < 16; ++k)
        if (wv[k] > bv) { bv = wv[k]; best = k; }   // first-max (jnp.argmax)
    const float4 cf = reinterpret_cast<const float4*>(OP2POLY)[best];

    float C[NGATE * 4];   // lands in SGPRs via readlane
#pragma unroll
    for (int gg = 0; gg < NGATE; ++gg) {
        C[4 * gg + 0] = readlane_f(cf.x, gg);
        C[4 * gg + 1] = readlane_f(cf.y, gg);
        C[4 * gg + 2] = readlane_f(cf.z, gg);
        C[4 * gg + 3] = readlane_f(cf.w, gg);
    }

    // ---- leaf descriptors (scalar loads; uniform addresses) ----
    int   voff[NLEAF];   // element offset vs biased base; always >= 0 at use
    float fm[NLEAF];     // column halo mask (lanes 0 / 63)
    int   dyv[NLEAF];
#pragma unroll
    for (int n = 0; n < NLEAF; ++n) {
        const int ch = ci[oc * NLEAF + n];
        const int dy = py[oc * NLEAF + n] - 1;
        const int dx = px[oc * NLEAF + n] - 1;
        const int c  = lane + dx;
        const int ccl = min(max(c, 0), W_ - 1);
        voff[n] = ch * IMG + (row0 + dy) * W_ + ccl + W_;   // +W_ bias
        fm[n]   = ((unsigned)c < (unsigned)W_) ? 1.0f : 0.0f;
        dyv[n]  = dy;
    }
    const float* xb = x + ((size_t)b * CIN * IMG) - W_;     // bias compensation

    // ---- k=0 loads (row-clamped + row+col masked at load) ----
    float acc[NLEAF];
#pragma unroll
    for (int n = 0; n < NLEAF; ++n) {
        const bool bad = (row0 + dyv[n]) < 0;               // only wave 0, dy=-1
        acc[n] = xb[voff[n] + (bad ? W_ : 0)] * (bad ? 0.0f : fm[n]);
    }

    const size_t obase =
        (((size_t)b * OCH + oc) * PH + (row0 >> 1)) * PW + (lane >> 1);

    float pprev = 0.0f;
#pragma unroll
    for (int k = 0; k < 16; ++k) {
        // prefetch row k+1 before consuming row k
        float nxt[NLEAF];
        if (k < 15) {
#pragma unroll
            for (int n = 0; n < NLEAF; ++n) {
                if (k == 14) {   // row 15: possible bottom halo (wave 3, dy=+1)
                    const bool bad = (row0 + 15 + dyv[n]) > (H_ - 1);
                    nxt[n] = xb[voff[n] + 15 * W_ - (bad ? W_ : 0)] *
                             (bad ? 0.0f : 1.0f);
                } else {
                    nxt[n] = xb[voff[n] + (k + 1) * W_];
                }
            }
        }

        // column masks (k=0 already fully masked at load time)
        float v[NLEAF];
#pragma unroll
        for (int n = 0; n < NLEAF; ++n)
            v[n] = (k == 0) ? acc[n] : acc[n] * fm[n];

        // 15-gate polynomial tree
        int go = 0;
#pragma unroll
        for (int lev = 8; lev >= 1; lev >>= 1) {
#pragma unroll
            for (int t = 0; t < lev; ++t) {
                const float a  = v[2 * t];
                const float bb = v[2 * t + 1];
                v[t] = C[(go + t) * 4] + C[(go + t) * 4 + 1] * a +
                       C[(go + t) * 4 + 2] * bb + C[(go + t) * 4 + 3] * (a * bb);
            }
            go += lev;
        }

        const float q = 1.0f - v[0];
        if (k & 1) {
            const float p  = pprev * q;                   // row-pair product
            const float pp = p * __shfl_xor(p, 1, 64);    // column-pair product
            if (!(lane & 1))
                out[obase + (size_t)(k >> 1) * PW] = 1.0f - pp;
        } else {
            pprev = q;
        }

        if (k < 15) {
#pragma unroll
            for (int n = 0; n < NLEAF; ++n) acc[n] = nxt[n];
        }
    }
}

extern "C" void kernel_launch(void* const* d_in, const int* in_sizes, int n_in,
                              void* d_out, int out_size, void* d_ws, size_t ws_size,
                              hipStream_t stream) {
    const float* x       = (const float*)d_in[0];
    const float* weights = (const float*)d_in[1];
    const int*   ci      = (const int*)d_in[2];
    const int*   px      = (const int*)d_in[3];
    const int*   py      = (const int*)d_in[4];
    float* out = (float*)d_out;
    (void)d_ws; (void)ws_size;

    logic_tree_fused<<<BATCH * OCH, 256, 0, stream>>>(x, weights, ci, px, py, out);
}